// Round 15
// baseline (25821.524 us; speedup 1.0000x reference)
//
#include <hip/hip_runtime.h>
#include <math.h>

typedef __attribute__((ext_vector_type(8))) __bf16          bf16x8;
typedef __attribute__((ext_vector_type(8))) unsigned short  ushort8;
typedef __attribute__((ext_vector_type(4))) float           f32x4;
typedef __attribute__((ext_vector_type(4))) unsigned int    u32x4;

constexpr int Bb = 128, Hh = 1024, Tt = 384, BH = Bb * Hh;
constexpr int NWG = 512, BLK = 256;   // 4 layers x 64 cg x 2 row-halves; 2 WGs/CU

// Fragment-linear X/H slot: 512 KB = 16 kcg x 32 blocks x 1 KB.
// block BI = kcg*32 + (row>>5)*8 + ((row>>4)&1)*4 + pl*2 + ks ; lane = kg*16+row16.
constexpr size_t SLOT_B  = 524288;
constexpr size_t OFF_H   = 1024;
constexpr size_t OFF_W   = OFF_H + 8 * SLOT_B;
constexpr size_t WBLK_B  = 12288;                     // per (m,cg,kcg): 12 blocks x 1 KB (48 gate-rows)
constexpr size_t OFF_X   = OFF_W + 4096ull * WBLK_B;  // 4 mats x 64 cg x 16 kcg
constexpr size_t WS_FULL = OFF_X + 384ull * SLOT_B;

__device__ __forceinline__ float b2f(unsigned short h) {
    unsigned u = ((unsigned)h) << 16;
    return __builtin_bit_cast(float, u);
}
__device__ __forceinline__ void split_bf16(float x, unsigned short& hi, unsigned short& lo) {
    unsigned u  = __builtin_bit_cast(unsigned, x);
    unsigned uh = u & 0xFFFF0000u;
    hi = (unsigned short)(uh >> 16);
    float rem = x - __builtin_bit_cast(float, uh);     // exact
    unsigned ur = __builtin_bit_cast(unsigned, rem);
    ur += 0x7FFFu + ((ur >> 16) & 1u);                 // RNE
    lo = (unsigned short)(ur >> 16);
}
__device__ __forceinline__ void split8(const float* src, ushort8& h8, ushort8& l8) {
    const float4* p4 = (const float4*)src;
    float4 a = p4[0], b = p4[1];
    float v[8] = {a.x, a.y, a.z, a.w, b.x, b.y, b.z, b.w};
    #pragma unroll
    for (int m = 0; m < 8; ++m) { unsigned short h, l; split_bf16(v[m], h, l); h8[m] = h; l8[m] = l; }
}
__device__ __forceinline__ void async16(const void* g, void* l) {
    __builtin_amdgcn_global_load_lds(
        (const __attribute__((address_space(1))) unsigned int*)g,
        (__attribute__((address_space(3))) unsigned int*)l, 16, 0, 0);
}

// ---------------- prologue kernels (fragment-linear emit, r10 layouts) ----------------

__global__ void wsplit_kernel(const float* __restrict__ W0i, const float* __restrict__ W0h,
                              const float* __restrict__ W1i, const float* __restrict__ W1h,
                              char* __restrict__ wbuf) {
    int t = blockIdx.x * 256 + threadIdx.x;
    if (t >= 4 * 64 * 16 * 48 * 8) return;
    int g8 = t & 7;
    int r  = (t >> 3) % 48;                  // ct*16 + jl
    int rest = (t >> 3) / 48;                // ((m*64+cg)*16+kcg)
    int kcg = rest & 15, cg = (rest >> 4) & 63, m = rest >> 10;
    const float* W = (m == 0) ? W0i : (m == 1) ? W0h : (m == 2) ? W1i : W1h;
    int ct = r >> 4, jl = r & 15;
    const float* src = W + (size_t)((ct << 10) + cg * 16 + jl) * 1024 + kcg * 64 + g8 * 8;
    ushort8 h8, l8; split8(src, h8, l8);
    int ks = (g8 >> 2) & 1, kg = g8 & 3, lane = kg * 16 + jl;
    char* blk = wbuf + (size_t)rest * WBLK_B;
    int off0 = (ct * 4 + ks) * 1024 + lane * 16;   // pl=0 ; pl=1 at +2048
    *(ushort8*)(blk + off0)        = h8;
    *(ushort8*)(blk + off0 + 2048) = l8;
}

__global__ void xsplit_kernel(const float* __restrict__ xin, char* __restrict__ xb) {
    int t = blockIdx.x * 256 + threadIdx.x;
    if (t >= 384 * 128 * 128) return;
    int g8 = t & 127, b = (t >> 7) & 127, tau = t >> 14;
    const float* src = xin + ((size_t)b * 384 + tau) * 1024 + g8 * 8;
    ushort8 h8, l8; split8(src, h8, l8);
    int kcg = g8 >> 3, gin = g8 & 7;
    int ks = (gin >> 2) & 1, kg = gin & 3;
    int lane = kg * 16 + (b & 15);
    int BI0 = kcg * 32 + (b >> 5) * 8 + ((b >> 4) & 1) * 4 + ks;
    char* dst = xb + (size_t)tau * SLOT_B + (size_t)BI0 * 1024 + lane * 16;
    *(ushort8*)dst          = h8;
    *(ushort8*)(dst + 2048) = l8;
}

__global__ void hinit_kernel(const float* __restrict__ h0, char* __restrict__ ws) {
    int t = blockIdx.x * 256 + threadIdx.x;
    if (t == 0) *(unsigned*)ws = 0;
    if (t >= 4 * 128 * 128) return;
    char* hs = ws + OFF_H;
    int g8 = t & 127, b = (t >> 7) & 127, si = t >> 14;   // si 0..3 -> slot 1,3,5,7
    ushort8 h8, l8;
    if (si < 2) {
        split8(h0 + (size_t)si * BH + (size_t)b * 1024 + g8 * 8, h8, l8);
    } else {
        #pragma unroll
        for (int m = 0; m < 8; ++m) { h8[m] = 0; l8[m] = 0; }
    }
    int kcg = g8 >> 3, gin = g8 & 7;
    int ks = (gin >> 2) & 1, kg = gin & 3;
    int lane = kg * 16 + (b & 15);
    int BI0 = kcg * 32 + (b >> 5) * 8 + ((b >> 4) & 1) * 4 + ks;
    char* dst = hs + (size_t)(si * 2 + 1) * SLOT_B + (size_t)BI0 * 1024 + lane * 16;
    *(ushort8*)dst          = h8;
    *(ushort8*)(dst + 2048) = l8;
}

// ---------------- main persistent kernel ----------------

__device__ __forceinline__ void grid_barrier(unsigned* cnt, unsigned target) {
    __syncthreads();   // drains vmcnt(0): sc1 h-stores at coherent point; ledger resets
    if (threadIdx.x == 0) {
        __hip_atomic_fetch_add(cnt, 1u, __ATOMIC_RELEASE, __HIP_MEMORY_SCOPE_AGENT);
        while (__hip_atomic_load(cnt, __ATOMIC_RELAXED, __HIP_MEMORY_SCOPE_AGENT) < target)
            __builtin_amdgcn_s_sleep(1);
    }
    __syncthreads();
}

#define WAITVM(N) asm volatile("s_waitcnt vmcnt(" #N ")" ::: "memory")

// r10-proven iteration: wait chunk CH landed -> barrier -> issue CH+3 -> compute CH.
#define GITER(CH, SLOT, ACC, WN, DOISS)                                  \
    WAITVM(WN);                                                          \
    asm volatile("" ::: "memory");                                       \
    __builtin_amdgcn_s_barrier();                                        \
    __builtin_amdgcn_sched_barrier(0);                                   \
    if (DOISS) { issueA((CH) + 3, arA[((SLOT) + 3) & 3]);                \
                 issueB((CH) + 3, ((SLOT) + 3) & 3); }                   \
    computeC(arA[SLOT], (SLOT), ACC);

// MODE: 0 = no-ws fallback (on-the-fly layer0 X) ; 1 = xsplit image
template<int MODE>
__global__ __launch_bounds__(BLK, 2) void gru_persistent(
    const float* __restrict__ xin,
    const float* __restrict__ bih0, const float* __restrict__ bhh0,
    const float* __restrict__ bih1, const float* __restrict__ bhh1,
    unsigned* __restrict__ cnt, char* __restrict__ ws)
{
    __shared__ char Bs[4][12288];    // 48 KiB: B 4-deep (2 WGs/CU -> 96 KiB)

    char*       hs = ws + OFF_H;
    const char* wb = ws + OFF_W;
    const char* xs = ws + OFF_X;

    // bid = layer*128 + rh*64 + cg  -> siblings (rh 0/1) are bids +-64: same XCD (64%8==0)
    const int bid = blockIdx.x, layer = bid >> 7;
    const int jw = bid & 127, rh = jw >> 6, cg = jw & 63;
    const int jbase = cg * 16;
    const int tid = threadIdx.x, lane = tid & 63, wv = tid >> 6;   // 4 waves x 16 rows

    const float* bih = (layer & 1) ? bih1 : bih0;
    const float* bhh = (layer & 1) ? bhh1 : bhh0;
    const int jl = lane & 15;
    const int jcol = jbase + jl;
    const float b_ir = bih[jcol],          b_hr = bhh[jcol];
    const float b_iz = bih[Hh + jcol],     b_hz = bhh[Hh + jcol];
    const float b_in = bih[2 * Hh + jcol], b_hn = bhh[2 * Hh + jcol];

    const int kcg_j = jcol >> 6, ks_j = (jcol >> 5) & 1, kg_j = (jcol >> 3) & 3, e_j = jcol & 7;
    const int rowBI = (rh * 2 + (wv >> 1)) * 8 + (wv & 1) * 4;   // wave's A block base (per kcg)

    auto hoff = [&](int pl, int q) -> size_t {
        return (size_t)(kcg_j * 32 + rowBI + pl * 2 + ks_j) * 1024
             + (size_t)(kg_j * 16 + (lane >> 4) * 4 + q) * 16 + e_j * 2;
    };

    float hreg[4];          // h_old: [q], rows b = rh*64 + wv*16 + (lane>>4)*4 + q
    const bool fb0 = (MODE == 0) && (layer == 0);

    unsigned target = NWG;
    for (int s = 0; s < Tt + 3; ++s, target += NWG) {
        const int tau = s - layer;
        if (tau >= 0 && tau < Tt) {
            const char* Axb = (layer == 0) ? (xs + (size_t)tau * SLOT_B)
                                           : (hs + (size_t)(((layer - 1) * 2) + (tau & 1)) * SLOT_B);
            const char* Ahb = hs + (size_t)((layer * 2) + ((tau - 1) & 1)) * SLOT_B;
            char*       Hd  = hs + (size_t)((layer * 2) + (tau & 1)) * SLOT_B;

            if (tau == 0) {
                if (layer < 2) {
                    #pragma unroll
                    for (int q = 0; q < 4; ++q) {
                        unsigned short hi = __hip_atomic_load(
                            (const unsigned short*)(Ahb + hoff(0, q)),
                            __ATOMIC_RELAXED, __HIP_MEMORY_SCOPE_AGENT);
                        unsigned short lo = __hip_atomic_load(
                            (const unsigned short*)(Ahb + hoff(1, q)),
                            __ATOMIC_RELAXED, __HIP_MEMORY_SCOPE_AGENT);
                        hreg[q] = b2f(hi) + b2f(lo);
                    }
                    asm volatile("s_waitcnt vmcnt(0)" ::: "memory");  // clean ledger
                } else {
                    #pragma unroll
                    for (int i = 0; i < 4; ++i) hreg[i] = 0.f;
                }
            }

            // ---- staging: chunk ch in [0,32): ch<16 = X-stream, else H-stream ----
            auto issueA = [&](int ch, u32x4* fr) {       // 4 asm loads -> VGPR frags (16 rows)
                const char* p = ((ch < 16) ? Axb : Ahb)
                              + ((size_t)(ch & 15) << 15) + ((size_t)rowBI << 10) + (lane << 4);
                const bool coh = !(ch < 16 && layer == 0);   // dynamic h tiles: coherent
                if (coh) {
                    asm volatile("global_load_dwordx4 %0, %1, off sc0 sc1"             : "=v"(fr[0]) : "v"(p));
                    asm volatile("global_load_dwordx4 %0, %1, off offset:1024 sc0 sc1" : "=v"(fr[1]) : "v"(p));
                    asm volatile("global_load_dwordx4 %0, %1, off offset:2048 sc0 sc1" : "=v"(fr[2]) : "v"(p));
                    asm volatile("global_load_dwordx4 %0, %1, off offset:3072 sc0 sc1" : "=v"(fr[3]) : "v"(p));
                } else {
                    asm volatile("global_load_dwordx4 %0, %1, off"             : "=v"(fr[0]) : "v"(p));
                    asm volatile("global_load_dwordx4 %0, %1, off offset:1024" : "=v"(fr[1]) : "v"(p));
                    asm volatile("global_load_dwordx4 %0, %1, off offset:2048" : "=v"(fr[2]) : "v"(p));
                    asm volatile("global_load_dwordx4 %0, %1, off offset:3072" : "=v"(fr[3]) : "v"(p));
                }
            };
            auto issueB = [&](int ch, int buf) {         // 3 DMA -> LDS (cached weights)
                const int m = (layer & 1) * 2 + (ch < 16 ? 0 : 1);
                const char* Wb = wb + (size_t)(((m * 64 + cg) << 4) + (ch & 15)) * WBLK_B;
                char* L = &Bs[buf][0];
                #pragma unroll
                for (int i = 0; i < 3; ++i) {
                    int seg = wv + i * 4;                // 12 segs / 4 waves
                    async16(Wb + seg * 1024 + lane * 16, L + seg * 1024);
                }
            };
            auto fragX = [&](int ch, u32x4* fr) {        // MODE0: on-the-fly layer-0 X frags
                const int kcg = ch & 15;
                #pragma unroll
                for (int ks = 0; ks < 2; ++ks) {
                    int row = rh * 64 + wv * 16 + (lane & 15);
                    int k0  = kcg * 64 + ks * 32 + (lane >> 4) * 8;
                    ushort8 h8, l8;
                    split8(xin + ((size_t)row * 384 + tau) * 1024 + k0, h8, l8);
                    fr[ks]     = __builtin_bit_cast(u32x4, h8);
                    fr[2 + ks] = __builtin_bit_cast(u32x4, l8);
                }
            };
            auto computeC = [&](u32x4* fa, int buf, f32x4 (&acc)[3]) {
                const char* B = &Bs[buf][0];
                __builtin_amdgcn_s_setprio(1);
                #pragma unroll
                for (int ks = 0; ks < 2; ++ks) {
                    bf16x8 Ah = __builtin_bit_cast(bf16x8, fa[ks]);
                    bf16x8 Al = __builtin_bit_cast(bf16x8, fa[2 + ks]);
                    #pragma unroll
                    for (int ct = 0; ct < 3; ++ct) {
                        bf16x8 Bh = __builtin_bit_cast(bf16x8, *(const ushort8*)(B + (ct*4 + ks)*1024 + lane*16));
                        bf16x8 Bl = __builtin_bit_cast(bf16x8, *(const ushort8*)(B + (ct*4 + ks)*1024 + 2048 + lane*16));
                        f32x4 c = acc[ct];
                        c = __builtin_amdgcn_mfma_f32_16x16x32_bf16(Ah, Bh, c, 0, 0, 0);
                        c = __builtin_amdgcn_mfma_f32_16x16x32_bf16(Al, Bh, c, 0, 0, 0);
                        c = __builtin_amdgcn_mfma_f32_16x16x32_bf16(Ah, Bl, c, 0, 0, 0);
                        acc[ct] = c;
                    }
                }
                __builtin_amdgcn_s_setprio(0);
            };

            f32x4 accX[3], accH[3];
            const f32x4 zv = {0.f, 0.f, 0.f, 0.f};
            #pragma unroll
            for (int ct = 0; ct < 3; ++ct) { accX[ct] = zv; accH[ct] = zv; }

            u32x4 arA[4][4];   // A-fragment ring, static slots only

            if (!fb0) {
                // prologue: chunks 0,1,2 in flight (21 loads/wave)
                issueA(0, arA[0]); issueB(0, 0);
                issueA(1, arA[1]); issueB(1, 1);
                issueA(2, arA[2]); issueB(2, 2);
                for (int c4 = 0; c4 < 16; c4 += 4) {        // X chunks 0..15
                    GITER(c4 + 0, 0, accX, 14, true);
                    GITER(c4 + 1, 1, accX, 14, true);
                    GITER(c4 + 2, 2, accX, 14, true);
                    GITER(c4 + 3, 3, accX, 14, true);
                }
                for (int c4 = 16; c4 < 28; c4 += 4) {       // H chunks 16..27
                    GITER(c4 + 0, 0, accH, 14, true);
                    GITER(c4 + 1, 1, accH, 14, true);
                    GITER(c4 + 2, 2, accH, 14, true);
                    GITER(c4 + 3, 3, accH, 14, true);
                }
                GITER(28, 0, accH, 14, true);               // issues 31
                GITER(29, 1, accH, 14, false);
                GITER(30, 2, accH, 7,  false);
                GITER(31, 3, accH, 0,  false);
            } else {
                // fallback: 2-buf loop, one barrier per chunk
                for (int ch = 0; ch < 32; ++ch) {
                    if (ch < 16) fragX(ch, arA[0]); else issueA(ch, arA[0]);
                    issueB(ch, ch & 1);
                    WAITVM(0);
                    asm volatile("" ::: "memory");
                    __builtin_amdgcn_s_barrier();
                    __builtin_amdgcn_sched_barrier(0);
                    if (ch < 16) computeC(arA[0], ch & 1, accX);
                    else         computeC(arA[0], ch & 1, accH);
                }
            }

            // ---- gates + state update; h as sc1 atomic bf16 pairs (coherent push) ----
            #pragma unroll
            for (int q = 0; q < 4; ++q) {
                float rp = accX[0][q] + accH[0][q] + b_ir + b_hr;
                float zp = accX[1][q] + accH[1][q] + b_iz + b_hz;
                float xn = accX[2][q] + b_in;
                float hn = accH[2][q] + b_hn;
                float r  = 1.0f / (1.0f + expf(-rp));
                float z  = 1.0f / (1.0f + expf(-zp));
                float n  = tanhf(xn + r * hn);
                float h  = (1.0f - z) * n + z * hreg[q];
                hreg[q] = h;
                unsigned short hi, lo; split_bf16(h, hi, lo);
                __hip_atomic_store((unsigned short*)(Hd + hoff(0, q)), hi,
                                   __ATOMIC_RELAXED, __HIP_MEMORY_SCOPE_AGENT);
                __hip_atomic_store((unsigned short*)(Hd + hoff(1, q)), lo,
                                   __ATOMIC_RELAXED, __HIP_MEMORY_SCOPE_AGENT);
            }
        }
        grid_barrier(cnt, target);
    }
}

__global__ void pred_kernel(const char* __restrict__ slot,
                            const float* __restrict__ linW,
                            const float* __restrict__ linb,
                            float* __restrict__ out) {
    const int b = blockIdx.x, l = threadIdx.x;   // 64 threads
    const int rpart = (b >> 5) * 8 + ((b >> 4) & 1) * 4;
    float s = 0.f;
    for (int u = l; u < Hh; u += 64) {
        int BI0 = (u >> 6) * 32 + rpart + ((u >> 5) & 1);
        size_t o = (size_t)BI0 * 1024 + (size_t)(((u >> 3) & 3) * 16 + (b & 15)) * 16 + (u & 7) * 2;
        float hv = b2f(*(const unsigned short*)(slot + o))
                 + b2f(*(const unsigned short*)(slot + o + 2048));
        s += hv * linW[u];
    }
    #pragma unroll
    for (int off = 32; off > 0; off >>= 1) s += __shfl_down(s, off);
    if (l == 0) out[b] = s + linb[0];
}

extern "C" void kernel_launch(void* const* d_in, const int* in_sizes, int n_in,
                              void* d_out, int out_size, void* d_ws, size_t ws_size,
                              hipStream_t stream) {
    const float* rand_in = (const float*)d_in[1];
    const float* h0      = (const float*)d_in[2];
    const float* Wih0    = (const float*)d_in[7];
    const float* Whh0    = (const float*)d_in[8];
    const float* bih0    = (const float*)d_in[9];
    const float* bhh0    = (const float*)d_in[10];
    const float* Wih1    = (const float*)d_in[11];
    const float* Whh1    = (const float*)d_in[12];
    const float* bih1    = (const float*)d_in[13];
    const float* bhh1    = (const float*)d_in[14];
    const float* linW    = (const float*)d_in[15];
    const float* linb    = (const float*)d_in[16];
    float* out = (float*)d_out;

    char*     ws  = (char*)d_ws;
    unsigned* cnt = (unsigned*)d_ws;
    char*     hsl = ws + OFF_H;

    const bool xsl = (ws_size >= WS_FULL);

    wsplit_kernel<<<6144, 256, 0, stream>>>(Wih0, Whh0, Wih1, Whh1, ws + OFF_W);
    hinit_kernel<<<256, 256, 0, stream>>>(h0, ws);
    if (xsl) {
        xsplit_kernel<<<24576, 256, 0, stream>>>(rand_in, ws + OFF_X);
        gru_persistent<1><<<NWG, BLK, 0, stream>>>(rand_in, bih0, bhh0, bih1, bhh1, cnt, ws);
    } else {
        gru_persistent<0><<<NWG, BLK, 0, stream>>>(rand_in, bih0, bhh0, bih1, bhh1, cnt, ws);
    }
    pred_kernel<<<Bb, 64, 0, stream>>>(hsl + 7 * SLOT_B, linW, linb, out);
}

// Round 16
// 13518.820 us; speedup vs baseline: 1.9100x; 1.9100x over previous
//
#include <hip/hip_runtime.h>
#include <math.h>

typedef __attribute__((ext_vector_type(8))) __bf16          bf16x8;
typedef __attribute__((ext_vector_type(8))) unsigned short  ushort8;
typedef __attribute__((ext_vector_type(4))) float           f32x4;
typedef __attribute__((ext_vector_type(4))) unsigned int    u32x4;

constexpr int Bb = 128, Hh = 1024, Tt = 384, BH = Bb * Hh;
constexpr int NWG = 256, BLK = 256;   // 4 layers x 64 jwg (16 jcols), 4 waves/WG

// Fragment-linear X/H slot: 512 KB = 16 kcg x 32 blocks x 1 KB.
// block BI = kcg*32 + rg*8 + rb*4 + pl*2 + ks ; lane = kg*16 + row16 at lane*16.
constexpr size_t SLOT_B  = 524288;
constexpr size_t OFF_H   = 1024;
constexpr size_t OFF_W   = OFF_H + 8 * SLOT_B;
constexpr size_t WBLK_B  = 12288;                     // per (m,jwg,kcg): 12 blocks x 1 KB
constexpr size_t OFF_X   = OFF_W + 4096ull * WBLK_B;  // 4 mats x 64 jwg x 16 kcg
constexpr size_t WS_FULL = OFF_X + 384ull * SLOT_B;

__device__ __forceinline__ float b2f(unsigned short h) {
    unsigned u = ((unsigned)h) << 16;
    return __builtin_bit_cast(float, u);
}
__device__ __forceinline__ void split_bf16(float x, unsigned short& hi, unsigned short& lo) {
    unsigned u  = __builtin_bit_cast(unsigned, x);
    unsigned uh = u & 0xFFFF0000u;
    hi = (unsigned short)(uh >> 16);
    float rem = x - __builtin_bit_cast(float, uh);     // exact
    unsigned ur = __builtin_bit_cast(unsigned, rem);
    ur += 0x7FFFu + ((ur >> 16) & 1u);                 // RNE
    lo = (unsigned short)(ur >> 16);
}
__device__ __forceinline__ void split8(const float* src, ushort8& h8, ushort8& l8) {
    const float4* p4 = (const float4*)src;
    float4 a = p4[0], b = p4[1];
    float v[8] = {a.x, a.y, a.z, a.w, b.x, b.y, b.z, b.w};
    #pragma unroll
    for (int m = 0; m < 8; ++m) { unsigned short h, l; split_bf16(v[m], h, l); h8[m] = h; l8[m] = l; }
}
__device__ __forceinline__ void async16(const void* g, void* l) {
    __builtin_amdgcn_global_load_lds(
        (const __attribute__((address_space(1))) unsigned int*)g,
        (__attribute__((address_space(3))) unsigned int*)l, 16, 0, 0);
}

// ---------------- prologue kernels (fragment-linear emit, r10 layouts) ----------------

__global__ void wsplit_kernel(const float* __restrict__ W0i, const float* __restrict__ W0h,
                              const float* __restrict__ W1i, const float* __restrict__ W1h,
                              char* __restrict__ wbuf) {
    int t = blockIdx.x * 256 + threadIdx.x;
    if (t >= 4 * 64 * 16 * 48 * 8) return;
    int g8 = t & 7;
    int r  = (t >> 3) % 48;                  // ct*16 + jl
    int rest = (t >> 3) / 48;                // ((m*64+jwg)*16+kcg)
    int kcg = rest & 15, jwg = (rest >> 4) & 63, m = rest >> 10;
    const float* W = (m == 0) ? W0i : (m == 1) ? W0h : (m == 2) ? W1i : W1h;
    int ct = r >> 4, jl = r & 15;
    const float* src = W + (size_t)((ct << 10) + jwg * 16 + jl) * 1024 + kcg * 64 + g8 * 8;
    ushort8 h8, l8; split8(src, h8, l8);
    int ks = (g8 >> 2) & 1, kg = g8 & 3, lane = kg * 16 + jl;
    char* blk = wbuf + (size_t)rest * WBLK_B;
    int off0 = (ct * 4 + ks) * 1024 + lane * 16;   // pl=0 ; pl=1 at +2048
    *(ushort8*)(blk + off0)        = h8;
    *(ushort8*)(blk + off0 + 2048) = l8;
}

__global__ void xsplit_kernel(const float* __restrict__ xin, char* __restrict__ xb) {
    int t = blockIdx.x * 256 + threadIdx.x;
    if (t >= 384 * 128 * 128) return;
    int g8 = t & 127, b = (t >> 7) & 127, tau = t >> 14;
    const float* src = xin + ((size_t)b * 384 + tau) * 1024 + g8 * 8;
    ushort8 h8, l8; split8(src, h8, l8);
    int kcg = g8 >> 3, gin = g8 & 7;
    int ks = (gin >> 2) & 1, kg = gin & 3;
    int lane = kg * 16 + (b & 15);
    int BI0 = kcg * 32 + (b >> 5) * 8 + ((b >> 4) & 1) * 4 + ks;
    char* dst = xb + (size_t)tau * SLOT_B + (size_t)BI0 * 1024 + lane * 16;
    *(ushort8*)dst          = h8;
    *(ushort8*)(dst + 2048) = l8;
}

__global__ void hinit_kernel(const float* __restrict__ h0, char* __restrict__ ws) {
    int t = blockIdx.x * 256 + threadIdx.x;
    if (t == 0) *(unsigned*)ws = 0;
    if (t >= 4 * 128 * 128) return;
    char* hs = ws + OFF_H;
    int g8 = t & 127, b = (t >> 7) & 127, si = t >> 14;   // si 0..3 -> slot 1,3,5,7
    ushort8 h8, l8;
    if (si < 2) {
        split8(h0 + (size_t)si * BH + (size_t)b * 1024 + g8 * 8, h8, l8);
    } else {
        #pragma unroll
        for (int m = 0; m < 8; ++m) { h8[m] = 0; l8[m] = 0; }
    }
    int kcg = g8 >> 3, gin = g8 & 7;
    int ks = (gin >> 2) & 1, kg = gin & 3;
    int lane = kg * 16 + (b & 15);
    int BI0 = kcg * 32 + (b >> 5) * 8 + ((b >> 4) & 1) * 4 + ks;
    char* dst = hs + (size_t)(si * 2 + 1) * SLOT_B + (size_t)BI0 * 1024 + lane * 16;
    *(ushort8*)dst          = h8;
    *(ushort8*)(dst + 2048) = l8;
}

// ---------------- main persistent kernel ----------------

__device__ __forceinline__ void grid_barrier(unsigned* cnt, unsigned target) {
    __syncthreads();   // drains vmcnt(0): sc1 h-stores at coherent point; ledger resets
    if (threadIdx.x == 0) {
        __hip_atomic_fetch_add(cnt, 1u, __ATOMIC_RELEASE, __HIP_MEMORY_SCOPE_AGENT);
        while (__hip_atomic_load(cnt, __ATOMIC_RELAXED, __HIP_MEMORY_SCOPE_AGENT) < target)
            __builtin_amdgcn_s_sleep(1);
    }
    __syncthreads();
}

#define WAITVM(N) asm volatile("s_waitcnt vmcnt(" #N ")" ::: "memory")

// distance-5 iteration: wait chunk CH landed -> barrier -> issue CH+5 -> compute CH.
// SL = CH % 6 (consume slot), ISL = (CH+5) % 6 (issue slot).
#define GITER(CH, SL, ISL, ACC, WN, DOISS)                               \
    WAITVM(WN);                                                          \
    asm volatile("" ::: "memory");                                       \
    __builtin_amdgcn_s_barrier();                                        \
    __builtin_amdgcn_sched_barrier(0);                                   \
    if (DOISS) { issueA((CH) + 5, arA[ISL]);                             \
                 issueB((CH) + 5, ISL); }                                \
    computeC(arA[SL], (SL), ACC);

// MODE: 0 = no-ws fallback (on-the-fly layer0 X) ; 1 = xsplit image
template<int MODE>
__global__ __launch_bounds__(BLK, 1) void gru_persistent(
    const float* __restrict__ xin,
    const float* __restrict__ bih0, const float* __restrict__ bhh0,
    const float* __restrict__ bih1, const float* __restrict__ bhh1,
    unsigned* __restrict__ cnt, char* __restrict__ ws)
{
    __shared__ char Bs[6][12288];    // 72 KiB: B 6-deep, fragment-linear

    char*       hs = ws + OFF_H;
    const char* wb = ws + OFF_W;
    const char* xs = ws + OFF_X;

    const int bid = blockIdx.x, layer = bid >> 6, jwg = bid & 63, jbase = jwg * 16;
    const int tid = threadIdx.x, lane = tid & 63, rg = tid >> 6;   // 4 waves = 4 row groups

    const float* bih = (layer & 1) ? bih1 : bih0;
    const float* bhh = (layer & 1) ? bhh1 : bhh0;
    const int jl = lane & 15;
    const int jcol = jbase + jl;
    const float b_ir = bih[jcol],          b_hr = bhh[jcol];
    const float b_iz = bih[Hh + jcol],     b_hz = bhh[Hh + jcol];
    const float b_in = bih[2 * Hh + jcol], b_hn = bhh[2 * Hh + jcol];

    const int kcg_j = jcol >> 6, ks_j = (jcol >> 5) & 1, kg_j = (jcol >> 3) & 3, e_j = jcol & 7;
    const int baseBI = kcg_j * 32 + rg * 8 + ks_j;
    auto hoff = [&](int rb, int pl, int q) -> size_t {
        return (size_t)(baseBI + rb * 4 + pl * 2) * 1024
             + (size_t)(kg_j * 16 + (lane >> 4) * 4 + q) * 16 + e_j * 2;
    };

    float hreg[8];          // h_old: [rb][q]
    const bool fb0 = (MODE == 0) && (layer == 0);

    unsigned target = NWG;
    for (int s = 0; s < Tt + 3; ++s, target += NWG) {
        const int tau = s - layer;
        if (tau >= 0 && tau < Tt) {
            const char* Axb = (layer == 0) ? (xs + (size_t)tau * SLOT_B)
                                           : (hs + (size_t)(((layer - 1) * 2) + (tau & 1)) * SLOT_B);
            const char* Ahb = hs + (size_t)((layer * 2) + ((tau - 1) & 1)) * SLOT_B;
            char*       Hd  = hs + (size_t)((layer * 2) + (tau & 1)) * SLOT_B;

            if (tau == 0) {
                if (layer < 2) {
                    #pragma unroll
                    for (int rb = 0; rb < 2; ++rb)
                        #pragma unroll
                        for (int q = 0; q < 4; ++q) {
                            unsigned short hi = __hip_atomic_load(
                                (const unsigned short*)(Ahb + hoff(rb, 0, q)),
                                __ATOMIC_RELAXED, __HIP_MEMORY_SCOPE_AGENT);
                            unsigned short lo = __hip_atomic_load(
                                (const unsigned short*)(Ahb + hoff(rb, 1, q)),
                                __ATOMIC_RELAXED, __HIP_MEMORY_SCOPE_AGENT);
                            hreg[rb * 4 + q] = b2f(hi) + b2f(lo);
                        }
                    asm volatile("s_waitcnt vmcnt(0)" ::: "memory");  // clean ledger
                } else {
                    #pragma unroll
                    for (int i = 0; i < 8; ++i) hreg[i] = 0.f;
                }
            }

            // ---- staging: chunk ch in [0,32): ch<16 = X-stream, else H-stream ----
            auto issueA = [&](int ch, u32x4* fr) {       // 8 asm loads -> VGPR frags
                const char* base = ((ch < 16) ? Axb : Ahb)
                                 + ((size_t)(ch & 15) << 15) + (rg << 13) + (lane << 4);
                const bool coh = !(ch < 16 && layer == 0);
                #pragma unroll
                for (int rb = 0; rb < 2; ++rb) {
                    const char* p = base + (rb << 12);
                    if (coh) {
                        asm volatile("global_load_dwordx4 %0, %1, off sc0 sc1"             : "=v"(fr[rb*4+0]) : "v"(p));
                        asm volatile("global_load_dwordx4 %0, %1, off offset:1024 sc0 sc1" : "=v"(fr[rb*4+1]) : "v"(p));
                        asm volatile("global_load_dwordx4 %0, %1, off offset:2048 sc0 sc1" : "=v"(fr[rb*4+2]) : "v"(p));
                        asm volatile("global_load_dwordx4 %0, %1, off offset:3072 sc0 sc1" : "=v"(fr[rb*4+3]) : "v"(p));
                    } else {
                        asm volatile("global_load_dwordx4 %0, %1, off"             : "=v"(fr[rb*4+0]) : "v"(p));
                        asm volatile("global_load_dwordx4 %0, %1, off offset:1024" : "=v"(fr[rb*4+1]) : "v"(p));
                        asm volatile("global_load_dwordx4 %0, %1, off offset:2048" : "=v"(fr[rb*4+2]) : "v"(p));
                        asm volatile("global_load_dwordx4 %0, %1, off offset:3072" : "=v"(fr[rb*4+3]) : "v"(p));
                    }
                }
            };
            auto issueB = [&](int ch, int buf) {         // 3 DMA -> LDS (cached)
                const int m = (layer & 1) * 2 + (ch < 16 ? 0 : 1);
                const char* Wb = wb + (size_t)(((m * 64 + jwg) << 4) + (ch & 15)) * WBLK_B;
                char* L = &Bs[buf][0];
                #pragma unroll
                for (int i = 0; i < 3; ++i) {
                    int seg = rg + i * 4;
                    async16(Wb + seg * 1024 + lane * 16, L + seg * 1024);
                }
            };
            auto fragX = [&](int ch, u32x4* fr) {        // MODE0: on-the-fly layer-0 X frags
                const int kcg = ch & 15;
                #pragma unroll
                for (int rb = 0; rb < 2; ++rb)
                    #pragma unroll
                    for (int ks = 0; ks < 2; ++ks) {
                        int row = rg * 32 + rb * 16 + (lane & 15);
                        int k0  = kcg * 64 + ks * 32 + (lane >> 4) * 8;
                        ushort8 h8, l8;
                        split8(xin + ((size_t)row * 384 + tau) * 1024 + k0, h8, l8);
                        fr[rb * 4 + ks]     = __builtin_bit_cast(u32x4, h8);
                        fr[rb * 4 + 2 + ks] = __builtin_bit_cast(u32x4, l8);
                    }
            };
            auto computeC = [&](u32x4* fr, int buf, f32x4 (&acc)[2][3]) {
                const char* B = &Bs[buf][0];
                __builtin_amdgcn_s_setprio(1);
                #pragma unroll
                for (int ks = 0; ks < 2; ++ks) {
                    bf16x8 Bh[3], Bl[3];
                    #pragma unroll
                    for (int ct = 0; ct < 3; ++ct) {
                        Bh[ct] = __builtin_bit_cast(bf16x8, *(const ushort8*)(B + (ct*4 + ks)*1024 + lane*16));
                        Bl[ct] = __builtin_bit_cast(bf16x8, *(const ushort8*)(B + (ct*4 + 2 + ks)*1024 + lane*16));
                    }
                    #pragma unroll
                    for (int rb = 0; rb < 2; ++rb) {
                        bf16x8 Ah = __builtin_bit_cast(bf16x8, fr[rb*4 + ks]);
                        bf16x8 Al = __builtin_bit_cast(bf16x8, fr[rb*4 + 2 + ks]);
                        #pragma unroll
                        for (int ct = 0; ct < 3; ++ct) {
                            f32x4 c = acc[rb][ct];
                            c = __builtin_amdgcn_mfma_f32_16x16x32_bf16(Ah, Bh[ct], c, 0, 0, 0);
                            c = __builtin_amdgcn_mfma_f32_16x16x32_bf16(Al, Bh[ct], c, 0, 0, 0);
                            c = __builtin_amdgcn_mfma_f32_16x16x32_bf16(Ah, Bl[ct], c, 0, 0, 0);
                            acc[rb][ct] = c;
                        }
                    }
                }
                __builtin_amdgcn_s_setprio(0);
            };

            f32x4 accX[2][3], accH[2][3];
            const f32x4 zv = {0.f, 0.f, 0.f, 0.f};
            #pragma unroll
            for (int rb = 0; rb < 2; ++rb)
                #pragma unroll
                for (int ct = 0; ct < 3; ++ct) { accX[rb][ct] = zv; accH[rb][ct] = zv; }

            u32x4 arA[6][8];   // A-fragment ring, static slots only (6-deep)

            if (!fb0) {
                // prologue: chunks 0..4 in flight (55 loads/wave)
                issueA(0, arA[0]); issueB(0, 0);
                issueA(1, arA[1]); issueB(1, 1);
                issueA(2, arA[2]); issueB(2, 2);
                issueA(3, arA[3]); issueB(3, 3);
                issueA(4, arA[4]); issueB(4, 4);
                // X chunks 0..15
                GITER(0, 0, 5, accX, 44, true);  GITER(1, 1, 0, accX, 44, true);
                GITER(2, 2, 1, accX, 44, true);  GITER(3, 3, 2, accX, 44, true);
                GITER(4, 4, 3, accX, 44, true);  GITER(5, 5, 4, accX, 44, true);
                GITER(6, 0, 5, accX, 44, true);  GITER(7, 1, 0, accX, 44, true);
                GITER(8, 2, 1, accX, 44, true);  GITER(9, 3, 2, accX, 44, true);
                GITER(10, 4, 3, accX, 44, true); GITER(11, 5, 4, accX, 44, true);
                GITER(12, 0, 5, accX, 44, true); GITER(13, 1, 0, accX, 44, true);
                GITER(14, 2, 1, accX, 44, true); GITER(15, 3, 2, accX, 44, true);
                // H chunks 16..31 (last issue at ch=26 -> chunk 31)
                GITER(16, 4, 3, accH, 44, true); GITER(17, 5, 4, accH, 44, true);
                GITER(18, 0, 5, accH, 44, true); GITER(19, 1, 0, accH, 44, true);
                GITER(20, 2, 1, accH, 44, true); GITER(21, 3, 2, accH, 44, true);
                GITER(22, 4, 3, accH, 44, true); GITER(23, 5, 4, accH, 44, true);
                GITER(24, 0, 5, accH, 44, true); GITER(25, 1, 0, accH, 44, true);
                GITER(26, 2, 1, accH, 44, true);
                GITER(27, 3, 2, accH, 44, false);
                GITER(28, 4, 3, accH, 33, false);
                GITER(29, 5, 4, accH, 22, false);
                GITER(30, 0, 5, accH, 11, false);
                GITER(31, 1, 0, accH, 0,  false);
            } else {
                // fallback: 2-buf loop, one barrier per chunk
                for (int ch = 0; ch < 32; ++ch) {
                    if (ch < 16) fragX(ch, arA[0]); else issueA(ch, arA[0]);
                    issueB(ch, ch & 1);
                    WAITVM(0);
                    asm volatile("" ::: "memory");
                    __builtin_amdgcn_s_barrier();
                    __builtin_amdgcn_sched_barrier(0);
                    if (ch < 16) computeC(arA[0], ch & 1, accX);
                    else         computeC(arA[0], ch & 1, accH);
                }
            }

            // ---- gates + state update; h as sc1 atomic bf16 pairs (coherent push) ----
            #pragma unroll
            for (int rb = 0; rb < 2; ++rb)
                #pragma unroll
                for (int q = 0; q < 4; ++q) {
                    float rp = accX[rb][0][q] + accH[rb][0][q] + b_ir + b_hr;
                    float zp = accX[rb][1][q] + accH[rb][1][q] + b_iz + b_hz;
                    float xn = accX[rb][2][q] + b_in;
                    float hn = accH[rb][2][q] + b_hn;
                    float r  = 1.0f / (1.0f + expf(-rp));
                    float z  = 1.0f / (1.0f + expf(-zp));
                    float n  = tanhf(xn + r * hn);
                    float h  = (1.0f - z) * n + z * hreg[rb * 4 + q];
                    hreg[rb * 4 + q] = h;
                    unsigned short hi, lo; split_bf16(h, hi, lo);
                    __hip_atomic_store((unsigned short*)(Hd + hoff(rb, 0, q)), hi,
                                       __ATOMIC_RELAXED, __HIP_MEMORY_SCOPE_AGENT);
                    __hip_atomic_store((unsigned short*)(Hd + hoff(rb, 1, q)), lo,
                                       __ATOMIC_RELAXED, __HIP_MEMORY_SCOPE_AGENT);
                }
        }
        grid_barrier(cnt, target);
    }
}

__global__ void pred_kernel(const char* __restrict__ slot,
                            const float* __restrict__ linW,
                            const float* __restrict__ linb,
                            float* __restrict__ out) {
    const int b = blockIdx.x, l = threadIdx.x;   // 64 threads
    const int rpart = (b >> 5) * 8 + ((b >> 4) & 1) * 4;
    float s = 0.f;
    for (int u = l; u < Hh; u += 64) {
        int BI0 = (u >> 6) * 32 + rpart + ((u >> 5) & 1);
        size_t o = (size_t)BI0 * 1024 + (size_t)(((u >> 3) & 3) * 16 + (b & 15)) * 16 + (u & 7) * 2;
        float hv = b2f(*(const unsigned short*)(slot + o))
                 + b2f(*(const unsigned short*)(slot + o + 2048));
        s += hv * linW[u];
    }
    #pragma unroll
    for (int off = 32; off > 0; off >>= 1) s += __shfl_down(s, off);
    if (l == 0) out[b] = s + linb[0];
}

extern "C" void kernel_launch(void* const* d_in, const int* in_sizes, int n_in,
                              void* d_out, int out_size, void* d_ws, size_t ws_size,
                              hipStream_t stream) {
    const float* rand_in = (const float*)d_in[1];
    const float* h0      = (const float*)d_in[2];
    const float* Wih0    = (const float*)d_in[7];
    const float* Whh0    = (const float*)d_in[8];
    const float* bih0    = (const float*)d_in[9];
    const float* bhh0    = (const float*)d_in[10];
    const float* Wih1    = (const float*)d_in[11];
    const float* Whh1    = (const float*)d_in[12];
    const float* bih1    = (const float*)d_in[13];
    const float* bhh1    = (const float*)d_in[14];
    const float* linW    = (const float*)d_in[15];
    const float* linb    = (const float*)d_in[16];
    float* out = (float*)d_out;

    char*     ws  = (char*)d_ws;
    unsigned* cnt = (unsigned*)d_ws;
    char*     hsl = ws + OFF_H;

    const bool xsl = (ws_size >= WS_FULL);

    wsplit_kernel<<<6144, 256, 0, stream>>>(Wih0, Whh0, Wih1, Whh1, ws + OFF_W);
    hinit_kernel<<<256, 256, 0, stream>>>(h0, ws);
    if (xsl) {
        xsplit_kernel<<<24576, 256, 0, stream>>>(rand_in, ws + OFF_X);
        gru_persistent<1><<<NWG, BLK, 0, stream>>>(rand_in, bih0, bhh0, bih1, bhh1, cnt, ws);
    } else {
        gru_persistent<0><<<NWG, BLK, 0, stream>>>(rand_in, bih0, bhh0, bih1, bhh1, cnt, ws);
    }
    pred_kernel<<<Bb, 64, 0, stream>>>(hsl + 7 * SLOT_B, linW, linb, out);
}